// Round 10
// baseline (98.424 us; speedup 1.0000x reference)
//
#include <hip/hip_runtime.h>
#include <math.h>

typedef unsigned short u16;
typedef unsigned int   u32;
typedef __attribute__((ext_vector_type(8))) short s8v;    // 8 bf16 (4 VGPRs)
typedef __attribute__((ext_vector_type(4))) float f4v;    // 16x16 MFMA C/D
typedef __attribute__((ext_vector_type(16))) float f16v;  // 32x32 MFMA C/D

#define NHEADS 12
#define SEQ 2048
#define CD 768
#define BB 2
#define QKVD 2304
#define CEXP 0.18033688f      // 0.125 * log2(e)
#define DEFER_THR 44.0f       // exp2(44*CEXP) ~ 245, bf16-safe

__device__ inline u16 f2bf(float f) {            // RNE fp32->bf16
    union { float f; unsigned u; } v; v.f = f;
    unsigned r = v.u + 0x7FFFu + ((v.u >> 16) & 1u);
    return (u16)(r >> 16);
}
__device__ inline u32 cvtpk_bf16(float lo, float hi) {
    u32 r;
    asm("v_cvt_pk_bf16_f32 %0, %1, %2" : "=v"(r) : "v"(lo), "v"(hi));
    return r;
}
__device__ inline float exp2_fast(float x) {     // native v_exp_f32: D = 2^S0
    float r;
    asm("v_exp_f32 %0, %1" : "=v"(r) : "v"(x));
    return r;
}
__device__ inline float max3f(float a, float b, float c) {
    float r;
    asm("v_max3_f32 %0, %1, %2, %3" : "=v"(r) : "v"(a), "v"(b), "v"(c));
    return r;
}

#define GLOAD16(SRC, DST) __builtin_amdgcn_global_load_lds(                 \
    (const __attribute__((address_space(1))) void*)(SRC),                   \
    (__attribute__((address_space(3))) void*)(DST), 16, 0, 0)

// XOR swizzle for [R][64] bf16 tiles (128B rows): u16 index   (GEMM + Ot)
#define SW(r, c) ((((r) << 6) + (c)) ^ (((r) & 7) << 3))
// XOR swizzle for [32][128] bf16 tiles (256B rows): u16 index (attention)
#define SW16(r, c) ((((r) << 7) + (c)) ^ (((r) & 15) << 3))

// ---------------------------------------------------------------------------
__global__ __launch_bounds__(256)
void cvt3_kernel(const float* __restrict__ a, u16* __restrict__ oa, int na,
                 const float* __restrict__ b, u16* __restrict__ ob, int nb,
                 const float* __restrict__ c, u16* __restrict__ oc) {
    const int i = (blockIdx.x * 256 + threadIdx.x) * 8;
    const float* src; u16* dst;
    if (i < na)           { src = a + i;            dst = oa + i; }
    else if (i < na + nb) { src = b + (i - na);     dst = ob + (i - na); }
    else                  { src = c + (i - na - nb); dst = oc + (i - na - nb); }
    const float4 x = *(const float4*)src;
    const float4 y = *(const float4*)(src + 4);
    s8v o;
    o[0] = (short)f2bf(x.x); o[1] = (short)f2bf(x.y);
    o[2] = (short)f2bf(x.z); o[3] = (short)f2bf(x.w);
    o[4] = (short)f2bf(y.x); o[5] = (short)f2bf(y.y);
    o[6] = (short)f2bf(y.z); o[7] = (short)f2bf(y.w);
    *(s8v*)dst = o;
}

// ---------------------------------------------------------------------------
// C = A @ W^T (+bias). 128xBN tile, BK=64, 4 waves. 1-D grid, XCD-swizzled.
// ---------------------------------------------------------------------------
template<int BN, int NBX, bool OUT_BF16, bool BIAS>
__global__ __launch_bounds__(256)
void gemm_bf16(const u16* __restrict__ A, const u16* __restrict__ W,
               const float* __restrict__ bias, void* __restrict__ Cout,
               int M, int N, int K) {
    constexpr int NF = BN / 32;
    __shared__ u16 As[8192];
    __shared__ u16 Bs[BN * 64];
    const int tid = threadIdx.x;
    const int l  = tid & 63, w = tid >> 6;
    const int wr = w >> 1, wc = w & 1;
    const int lq = l & 15, lg = l >> 4;

    const int fid = blockIdx.x;
    const int cpx = gridDim.x >> 3;
    const int swz = (fid & 7) * cpx + (fid >> 3);
    const int rowBase = (swz / NBX) << 7;
    const int colBase = (swz % NBX) * BN;

    f4v acc[4][NF];
    #pragma unroll
    for (int m = 0; m < 4; ++m)
        #pragma unroll
        for (int n = 0; n < NF; ++n)
            #pragma unroll
            for (int r = 0; r < 4; ++r) acc[m][n][r] = 0.f;

    const int chunk = l & 7;
    const int r8    = l >> 3;

    for (int kb = 0; kb < K; kb += 64) {
        __syncthreads();
        #pragma unroll
        for (int j = 0; j < 4; ++j) {
            const int rowA = (w << 5) + (j << 3) + r8;
            const int sc   = (chunk ^ (rowA & 7)) << 3;
            GLOAD16(A + (size_t)(rowBase + rowA) * K + kb + sc,
                    &As[(w << 11) + (j << 9)]);
        }
        #pragma unroll
        for (int j = 0; j < NF; ++j) {
            const int rowB = w * (BN / 4) + (j << 3) + r8;
            const int sc   = (chunk ^ (rowB & 7)) << 3;
            GLOAD16(W + (size_t)(colBase + rowB) * K + kb + sc,
                    &Bs[w * (BN * 16) + (j << 9)]);
        }
        __syncthreads();
        #pragma unroll
        for (int h = 0; h < 2; ++h) {
            const int kc = (h << 5) + (lg << 3);
            s8v af[4], bf[NF];
            #pragma unroll
            for (int m = 0; m < 4; ++m)
                af[m] = *(const s8v*)&As[SW((wr << 6) + (m << 4) + lq, kc)];
            #pragma unroll
            for (int n = 0; n < NF; ++n)
                bf[n] = *(const s8v*)&Bs[SW(wc * (BN / 2) + (n << 4) + lq, kc)];
            #pragma unroll
            for (int m = 0; m < 4; ++m)
                #pragma unroll
                for (int n = 0; n < NF; ++n)
                    acc[m][n] = __builtin_amdgcn_mfma_f32_16x16x32_bf16(
                        af[m], bf[n], acc[m][n], 0, 0, 0);
        }
    }

    #pragma unroll
    for (int m = 0; m < 4; ++m)
        #pragma unroll
        for (int r = 0; r < 4; ++r) {
            const int row = rowBase + (wr << 6) + (m << 4) + (lg << 2) + r;
            #pragma unroll
            for (int n = 0; n < NF; ++n) {
                const int col = colBase + wc * (BN / 2) + (n << 4) + lq;
                float v = acc[m][n][r];
                if (BIAS) v += bias[col];
                if (OUT_BF16) ((u16*)Cout)[(size_t)row * N + col] = f2bf(v);
                else        ((float*)Cout)[(size_t)row * N + col] = v;
            }
        }
}

// ---------------------------------------------------------------------------
// V-part transpose: qkvb [token][2304] (cols h*192+128..191) -> vT[bh][d][token]
// ---------------------------------------------------------------------------
__global__ __launch_bounds__(256)
void vtrans_kernel(const u16* __restrict__ qkvb, u16* __restrict__ vT) {
    __shared__ u16 T[64][66];
    const int bh = blockIdx.y;
    const int tt = blockIdx.x;
    const int b = bh / NHEADS, h = bh % NHEADS;
    const int r  = threadIdx.x >> 2;
    const int dc = (threadIdx.x & 3) << 4;
    const u16* src = qkvb + (size_t)(b * SEQ + tt * 64 + r) * QKVD
                   + h * 192 + 128 + dc;
    *(s8v*)&T[r][dc]     = *(const s8v*)(src);
    *(s8v*)&T[r][dc + 8] = *(const s8v*)(src + 8);
    __syncthreads();
    const int d  = threadIdx.x >> 2;
    const int tc = (threadIdx.x & 3) << 4;
    s8v o0, o1;
    #pragma unroll
    for (int j = 0; j < 8; ++j) {
        o0[j] = (short)T[tc + j][d];
        o1[j] = (short)T[tc + 8 + j][d];
    }
    u16* dst = vT + ((size_t)bh * 64 + d) * SEQ + tt * 64 + tc;
    *(s8v*)dst = o0;
    *(s8v*)(dst + 8) = o1;
}

// ---------------------------------------------------------------------------
// MFMA flash attention, 32x32x16 shape. 4 waves/block, wave owns 32 q-rows;
// KV-split x2 (g = w>>1, keys [g*1024,+1024), 16 tiles of 64).
// S^T = mfma(K, Q^T): lane q = l&31, 16 keys/reg-block -> softmax fully
// lane-local (pair l,l^32 merged only at epilogue). P packed to PV B-frags
// IN REGISTERS via 16 cvt_pk + 8 v_permlane32_swap (T12) -- no P LDS bounce.
// K/V staged via global_load_lds, inverse-swizzled per-lane source + linear
// dest (rule 21), [32][128] tiles, SW16 4-bit XOR -> all LDS at width floor.
// 2 barriers/tile: B_k after QK (stage K(t+1), covered by softmax+PV);
// B_v after PV (stage V(t+1), covered by next QK).
// LDS 40KB+512B -> 3 blocks/CU, grid 768 = 3x256 exact.
// ---------------------------------------------------------------------------
__global__ __launch_bounds__(256)
void attn_mfma(const u16* __restrict__ qkv, const u16* __restrict__ vT,
               u16* __restrict__ outb) {
    __shared__ u16 SL[20480];          // g0K|g0V|g1K|g1V (4x4096) | Q (4096)
    __shared__ float ML[128];          // Msh[64] | Lsh[64]
    const int tid = threadIdx.x;
    const int l  = tid & 63, w = tid >> 6;   // 4 waves
    const int g  = w >> 1, wl = w & 1;
    const int lq = l & 31;
    const int lh = l >> 5;

    const int fid = blockIdx.x;
    const int swz = (fid & 7) * 96 + (fid >> 3);
    const int q0 = (swz & 31) << 6;
    const int bh = swz >> 5;
    const int b = bh / NHEADS, hh = bh % NHEADS;
    const u16* base  = qkv + (size_t)b * SEQ * QKVD + hh * 192;
    const u16* baseK = base + 64;
    const u16* vbh   = vT + (size_t)bh * 64 * SEQ;

    const int kv0 = g << 10;
    u16* Kl = SL + (g << 13);          // [32][128] u16
    u16* Vl = Kl + 4096;
    u16* Ql = SL + 16384;
    float* Of32 = (float*)(SL + 8192); // [64][64] f32, aliases g1 K+V
    float* Msh = ML;
    float* Lsh = ML + 64;
    u16* Ot = SL + 16384;              // aliases Ql (dead after qf)

    // staging: inverse-swizzled per-lane sources, linear dest (rule 21).
    // dest granule G = wl*256 + i*64 + l  holds logical (r = G>>4,
    // cg = (G&15)^(r&15)); source row = (cg>>3)*32 + r, chunk = (cg&7)*8.
    u32 kso[4], vso[4];
    #pragma unroll
    for (int i = 0; i < 4; ++i) {
        const int r  = (wl << 4) + (i << 2) + (l >> 4);     // 0..31
        const int cg = (l & 15) ^ (r & 15);
        const int kk = ((cg >> 3) << 5) + r;                // key (K) / d (V)
        const int cc = (cg & 7) << 3;
        kso[i] = (u32)((kv0 + kk) * QKVD + cc);
        vso[i] = (u32)(kk * SEQ + kv0 + cc);
    }

    {   // prologue: stage tile 0 (K,V) + Q
        #pragma unroll
        for (int i = 0; i < 4; ++i) {
            GLOAD16(baseK + kso[i], &Kl[(wl << 11) + (i << 9)]);
            GLOAD16(vbh  + vso[i], &Vl[(wl << 11) + (i << 9)]);
        }
        const int qr = tid >> 3, qc = (tid & 7) << 3;
        const s8v qv0 = *(const s8v*)(base + (size_t)(q0 + qr) * QKVD + qc);
        const s8v qv1 = *(const s8v*)(base + (size_t)(q0 + 32 + qr) * QKVD + qc);
        *(s8v*)&Ql[SW16(qr, qc)]      = qv0;
        *(s8v*)&Ql[SW16(qr, 64 + qc)] = qv1;
    }
    __syncthreads();

    s8v qf[4];     // B-frag: col = q = wl*32+lq, k = d = ds*16 + 8*lh + e
    #pragma unroll
    for (int ds = 0; ds < 4; ++ds)
        qf[ds] = *(const s8v*)&Ql[SW16(lq, (wl << 6) + (ds << 4) + (lh << 3))];

    f16v z16;
    #pragma unroll
    for (int r = 0; r < 16; ++r) z16[r] = 0.f;
    f16v oa0 = z16, oa1 = z16;         // O^T[d][q]: d = krow(r)+4lh+32db
    float osum = 0.f, mrun = -3.0e38f;

    for (int t = 0; t < 16; ++t) {
        // ---- QK: S^T[key][q], key = krow(reg)+4lh+32kb ----
        s8v ka[8];
        #pragma unroll
        for (int kb = 0; kb < 2; ++kb)
            #pragma unroll
            for (int ds = 0; ds < 4; ++ds)
                ka[kb * 4 + ds] = *(const s8v*)
                    &Kl[SW16(lq, (kb << 6) + (ds << 4) + (lh << 3))];
        f16v s0 = z16, s1 = z16;
        __builtin_amdgcn_s_setprio(1);
        #pragma unroll
        for (int ds = 0; ds < 4; ++ds)
            s0 = __builtin_amdgcn_mfma_f32_32x32x16_bf16(ka[ds], qf[ds], s0, 0, 0, 0);
        #pragma unroll
        for (int ds = 0; ds < 4; ++ds)
            s1 = __builtin_amdgcn_mfma_f32_32x32x16_bf16(ka[4 + ds], qf[ds], s1, 0, 0, 0);
        __builtin_amdgcn_s_setprio(0);

        __syncthreads();               // B_k: all K(t) reads done
        if (t < 15) {                  // stage K(t+1): covered by softmax+PV
            const u16* sb = baseK + (size_t)(t + 1) * (64 * QKVD);
            #pragma unroll
            for (int i = 0; i < 4; ++i)
                GLOAD16(sb + kso[i], &Kl[(wl << 11) + (i << 9)]);
        }

        // ---- softmax (lane-local; pair l,l^32 merged at epilogue) ----
        float mxa = max3f(s0[0], s0[1], s0[2]);
        mxa = max3f(mxa, s0[3], s0[4]);  mxa = max3f(mxa, s0[5], s0[6]);
        mxa = max3f(mxa, s0[7], s0[8]);  mxa = max3f(mxa, s0[9], s0[10]);
        mxa = max3f(mxa, s0[11], s0[12]); mxa = max3f(mxa, s0[13], s0[14]);
        float mxb = max3f(s1[0], s1[1], s1[2]);
        mxb = max3f(mxb, s1[3], s1[4]);  mxb = max3f(mxb, s1[5], s1[6]);
        mxb = max3f(mxb, s1[7], s1[8]);  mxb = max3f(mxb, s1[9], s1[10]);
        mxb = max3f(mxb, s1[11], s1[12]); mxb = max3f(mxb, s1[13], s1[14]);
        float mx = max3f(mxa, s0[15], mxb);
        mx = fmaxf(mx, s1[15]);
        if (!__all(mx <= mrun + DEFER_THR)) {
            mx = fmaxf(mx, __shfl_xor(mx, 32));
            const float mn = fmaxf(mrun, mx);
            const float al = exp2_fast((mrun - mn) * CEXP);
            mrun = mn;
            #pragma unroll
            for (int r = 0; r < 16; ++r) { oa0[r] *= al; oa1[r] *= al; }
            osum *= al;
        }
        const float mC = -mrun * CEXP;
        #pragma unroll
        for (int r = 0; r < 16; ++r) {
            s0[r] = exp2_fast(fmaf(s0[r], CEXP, mC));
            s1[r] = exp2_fast(fmaf(s1[r], CEXP, mC));
        }
        {   // denominator partial (4 parallel chains)
            float a0 = s0[0] + s0[4], a1 = s0[1] + s0[5];
            float a2 = s0[2] + s0[6], a3 = s0[3] + s0[7];
            a0 += s0[8] + s0[12];  a1 += s0[9] + s0[13];
            a2 += s0[10] + s0[14]; a3 += s0[11] + s0[15];
            a0 += s1[0] + s1[4];   a1 += s1[1] + s1[5];
            a2 += s1[2] + s1[6];   a3 += s1[3] + s1[7];
            a0 += s1[8] + s1[12];  a1 += s1[9] + s1[13];
            a2 += s1[10] + s1[14]; a3 += s1[11] + s1[15];
            osum += (a0 + a1) + (a2 + a3);
        }

        // ---- P -> bf16 B-frags in registers (T12: cvt_pk + permlane32) ----
        s8v pf[4];
        #pragma unroll
        for (int s = 0; s < 2; ++s) {
            u32 A0 = cvtpk_bf16(s0[8*s+0], s0[8*s+1]);
            u32 B0 = cvtpk_bf16(s0[8*s+4], s0[8*s+5]);
            u32 A1 = cvtpk_bf16(s0[8*s+2], s0[8*s+3]);
            u32 B1 = cvtpk_bf16(s0[8*s+6], s0[8*s+7]);
            asm volatile("v_permlane32_swap_b32 %0, %1" : "+v"(A0), "+v"(B0));
            asm volatile("v_permlane32_swap_b32 %0, %1" : "+v"(A1), "+v"(B1));
            union { s8v v; u32 u[4]; } pu;
            pu.u[0] = A0; pu.u[1] = A1; pu.u[2] = B0; pu.u[3] = B1;
            pf[s] = pu.v;
        }
        #pragma unroll
        for (int s = 0; s < 2; ++s) {
            u32 A0 = cvtpk_bf16(s1[8*s+0], s1[8*s+1]);
            u32 B0 = cvtpk_bf16(s1[8*s+4], s1[8*s+5]);
            u32 A1 = cvtpk_bf16(s1[8*s+2], s1[8*s+3]);
            u32 B1 = cvtpk_bf16(s1[8*s+6], s1[8*s+7]);
            asm volatile("v_permlane32_swap_b32 %0, %1" : "+v"(A0), "+v"(B0));
            asm volatile("v_permlane32_swap_b32 %0, %1" : "+v"(A1), "+v"(B1));
            union { s8v v; u32 u[4]; } pu;
            pu.u[0] = A0; pu.u[1] = A1; pu.u[2] = B0; pu.u[3] = B1;
            pf[2 + s] = pu.v;
        }

        // ---- PV: O^T[d][q] += V^T x P^T ----
        s8v va[8];
        #pragma unroll
        for (int db = 0; db < 2; ++db)
            #pragma unroll
            for (int ks = 0; ks < 4; ++ks)
                va[db * 4 + ks] = *(const s8v*)
                    &Vl[SW16(lq, (db << 6) + (ks << 4) + (lh << 3))];
        __builtin_amdgcn_s_setprio(1);
        #pragma unroll
        for (int ks = 0; ks < 4; ++ks)
            oa0 = __builtin_amdgcn_mfma_f32_32x32x16_bf16(va[ks], pf[ks], oa0, 0, 0, 0);
        #pragma unroll
        for (int ks = 0; ks < 4; ++ks)
            oa1 = __builtin_amdgcn_mfma_f32_32x32x16_bf16(va[4 + ks], pf[ks], oa1, 0, 0, 0);
        __builtin_amdgcn_s_setprio(0);

        __syncthreads();               // B_v: all V(t) reads done
        if (t < 15) {                  // stage V(t+1): covered by next QK
            const u16* sb = vbh + (t + 1) * 64;
            #pragma unroll
            for (int i = 0; i < 4; ++i)
                GLOAD16(sb + vso[i], &Vl[(wl << 11) + (i << 9)]);
        }
    }

    // ---- epilogue: pair-merge denominator, merge g1 -> g0, write out ----
    const float osum_t = osum + __shfl_xor(osum, 32);
    const int wq = (wl << 5) + lq;
    if (g == 1) {
        if (lh == 0) { Msh[wq] = mrun; Lsh[wq] = osum_t; }
        #pragma unroll
        for (int r = 0; r < 16; ++r) {
            const int d0 = (r & 3) + ((r >> 2) << 3) + (lh << 2);
            Of32[d0 * 64 + wq]        = oa0[r];
            Of32[(d0 + 32) * 64 + wq] = oa1[r];
        }
    }
    __syncthreads();
    if (g == 0) {
        const float m1 = Msh[wq], l1 = Lsh[wq];
        const float M  = fmaxf(mrun, m1);
        const float w0 = exp2_fast((mrun - M) * CEXP);
        const float w1 = exp2_fast((m1 - M) * CEXP);
        const float inv = 1.f / (osum_t * w0 + l1 * w1);
        const float a0 = w0 * inv, a1 = w1 * inv;
        #pragma unroll
        for (int j = 0; j < 4; ++j) {
            const int d0 = (j << 3) + (lh << 2);
            const float v0 = oa0[4*j+0] * a0 + Of32[(d0+0)*64+wq] * a1;
            const float v1 = oa0[4*j+1] * a0 + Of32[(d0+1)*64+wq] * a1;
            const float v2 = oa0[4*j+2] * a0 + Of32[(d0+2)*64+wq] * a1;
            const float v3 = oa0[4*j+3] * a0 + Of32[(d0+3)*64+wq] * a1;
            *(u32*)&Ot[SW(wq, d0)]     = cvtpk_bf16(v0, v1);
            *(u32*)&Ot[SW(wq, d0 + 2)] = cvtpk_bf16(v2, v3);
            const float u0 = oa1[4*j+0] * a0 + Of32[(d0+32)*64+wq] * a1;
            const float u1 = oa1[4*j+1] * a0 + Of32[(d0+33)*64+wq] * a1;
            const float u2 = oa1[4*j+2] * a0 + Of32[(d0+34)*64+wq] * a1;
            const float u3 = oa1[4*j+3] * a0 + Of32[(d0+35)*64+wq] * a1;
            *(u32*)&Ot[SW(wq, d0 + 32)] = cvtpk_bf16(u0, u1);
            *(u32*)&Ot[SW(wq, d0 + 34)] = cvtpk_bf16(u2, u3);
        }
    }
    __syncthreads();
    {   // coalesced store of the 64x64 output tile
        const int row = tid >> 2, c0 = (tid & 3) << 4;
        const s8v o0 = *(const s8v*)&Ot[SW(row, c0)];
        const s8v o1 = *(const s8v*)&Ot[SW(row, c0 + 8)];
        u16* dst = outb + (size_t)(b * SEQ + q0 + row) * CD + hh * 64 + c0;
        *(s8v*)dst = o0;
        *(s8v*)(dst + 8) = o1;
    }
}

// ---------------------------------------------------------------------------
extern "C" void kernel_launch(void* const* d_in, const int* in_sizes, int n_in,
                              void* d_out, int out_size, void* d_ws, size_t ws_size,
                              hipStream_t stream) {
    const float* x     = (const float*)d_in[0];
    const float* w_qkv = (const float*)d_in[1];
    const float* w_mlp = (const float*)d_in[2];
    const float* b_mlp = (const float*)d_in[3];
    float* out = (float*)d_out;

    const int NX  = BB * SEQ * CD;        // 3,145,728
    const int NWQ = QKVD * CD;            // 1,769,472
    const int NWM = CD * CD;              //   589,824
    const int NQK = BB * SEQ * QKVD;      // 9,437,184
    const int NAT = BB * SEQ * CD;        // attn out
    u16* xb    = (u16*)d_ws;
    u16* wqkvb = xb + NX;
    u16* wmlpb = wqkvb + NWQ;
    u16* qkvb  = wmlpb + NWM;
    u16* attnb = qkvb + NQK;
    u16* vTb   = attnb + NAT;             // [24][64][2048]

    cvt3_kernel<<<(NX + NWQ + NWM) / 2048, 256, 0, stream>>>(
        x, xb, NX, w_qkv, wqkvb, NWQ, w_mlp, wmlpb);

    const int M = BB * SEQ;   // 4096
    {   // qkv = x @ w_qkv^T  -> bf16   (grid 576 = 18 cols x 32 rows)
        gemm_bf16<128, 18, true, false><<<576, 256, 0, stream>>>(
            xb, wqkvb, nullptr, qkvb, M, QKVD, CD);
    }
    {   // V-part transpose
        dim3 grid(SEQ / 64, BB * NHEADS);
        vtrans_kernel<<<grid, 256, 0, stream>>>(qkvb, vTb);
    }
    {   // attention (32x32 MFMA, 4 waves, KV-split x2, in-reg P)
        attn_mfma<<<768, 256, 0, stream>>>(qkvb, vTb, attnb);
    }
    {   // out = attn @ w_mlp^T + b  -> fp32 (grid 384 = 12 cols x 32 rows)
        gemm_bf16<64, 12, false, true><<<384, 256, 0, stream>>>(
            attnb, wmlpb, b_mlp, out, M, CD, CD);
    }
}